// Round 7
// baseline (404.311 us; speedup 1.0000x reference)
//
#include <hip/hip_runtime.h>
#include <stdint.h>

#define HW   1369      // 37*37 output pixels
#define QW   39        // padded row width
#define QP   1616      // padded plane rows per (b) in Xp
#define QT   1536      // q rows in x1 (per batch)
#define CIN  1024
#define CMID 512
#define KTOT 9216      // 9 * 1024
#define NTIL 144       // K-tiles: 16 cblocks(64) * 9 taps, cblock-major tap-inner
#define ASLOT 12288    // A slot stride in elements: 192 rows x 64 el (24576 B)

typedef float  f32x4  __attribute__((ext_vector_type(4)));
typedef __bf16 bf16x8 __attribute__((ext_vector_type(8)));

__device__ __forceinline__ uint16_t f2bf(float f) {
  uint32_t u = __float_as_uint(f);
  u += 0x7fffu + ((u >> 16) & 1u);
  return (uint16_t)(u >> 16);
}

// global -> LDS direct copy, 16B per lane. LDS dest = wave-uniform base + lane*16.
__device__ __forceinline__ void gll16(const void* g, void* l) {
  const __attribute__((address_space(1))) uint32_t* ga =
      (const __attribute__((address_space(1))) uint32_t*)(uintptr_t)g;
  __attribute__((address_space(3))) uint32_t* la =
      (__attribute__((address_space(3))) uint32_t*)(uint32_t)(uintptr_t)l;
  __builtin_amdgcn_global_load_lds(ga, la, 16, 0, 0);
}

// ---------- prep: fmap [b][c][h][w] f32 -> Xp [b][q][c] bf16 (padded, zeroed border) ----------
__global__ void k_pad_transpose(const float* __restrict__ fmap, uint16_t* __restrict__ Xp) {
  __shared__ float t[32][33];
  const int b = blockIdx.z;
  const int c0 = blockIdx.y * 32;
  const int p0 = blockIdx.x * 32;
  const int tx = threadIdx.x, ty = threadIdx.y;
  const float* src = fmap + ((size_t)b * CIN + c0) * HW + p0;
#pragma unroll
  for (int i = 0; i < 4; ++i) {
    int cc = ty + i * 8;
    t[cc][tx] = (p0 + tx < HW) ? src[(size_t)cc * HW + tx] : 0.f;
  }
  __syncthreads();
#pragma unroll
  for (int i = 0; i < 4; ++i) {
    int pl = ty + i * 8;
    int p = p0 + pl;
    if (p < HW) {
      int h = p / 37, w = p - h * 37;
      int q = (h + 1) * QW + (w + 1);
      Xp[((size_t)b * QP + q) * CIN + c0 + tx] = f2bf(t[tx][pl]);
    }
  }
}

// ---------- prep: W1 [o][c][3][3] f32 -> Apk [o][r*1024+c] bf16 ----------
__global__ void k_pack_w1(const float* __restrict__ W1, uint16_t* __restrict__ Apk) {
  int idx = blockIdx.x * 256 + threadIdx.x;
  if (idx >= 512 * KTOT) return;
  int o = idx / KTOT, k = idx - o * KTOT;
  int r = k >> 10, c = k & 1023;
  Apk[idx] = f2bf(W1[((size_t)o * CIN + c) * 9 + r]);
}

// ---------- prep: W2 [120][512] f32 -> W2p [128][512] bf16 ----------
__global__ void k_pack_w2(const float* __restrict__ W2, uint16_t* __restrict__ W2p) {
  int idx = blockIdx.x * 256 + threadIdx.x;
  int j = idx >> 9, o = idx & 511;
  W2p[idx] = (j < 120) ? f2bf(W2[j * 512 + o]) : (uint16_t)0;
}

// ---------- conv1: implicit GEMM, A via LDS (3 slots), B direct-to-register ----------
// BM=192 x BN=256 x BK=64, 8 waves (2M x 4N, wave 96x64), grid = exactly 256 blocks.
// A: gll16 -> 3 LDS slots (24KB each), XOR-swizzled; 3 loads/thread/tile.
// B: per-lane global_load_dwordx4 (L1/L2-hot weights), register double-buffer bvA/bvB.
// One barrier per tile (3 slots => stage(t+2) never hits the slot being read).
// vmcnt(3) per tile: drains A(t)+B(t), leaves A(t+1)'s 3 loads in flight.
__global__ __launch_bounds__(512, 2) void k_conv1(
    const uint16_t* __restrict__ Xp, const uint16_t* __restrict__ Apk,
    const float* __restrict__ b1, uint16_t* __restrict__ x1) {
  __shared__ __align__(16) uint16_t lds[3 * ASLOT];   // 73728 B

  const int tid  = threadIdx.x;
  const int wid  = tid >> 6, lane = tid & 63;
  const int lrow = lane & 15, lq = lane >> 4;
  const int wm   = wid >> 2,  wn = wid & 3;           // 2M x 4N

  // grid: 256 blocks = 8 XCDs x 32, mt-major within XCD
  const int bid = blockIdx.x;
  const int g   = (bid & 7) * 32 + (bid >> 3);
  const int mt  = g >> 1, nt = g & 1;
  const int batch = mt >> 3, qb = (mt & 7) * 192;
  const int o0 = nt * 256;
  const uint16_t* Xb = Xp + (size_t)batch * QP * CIN;

  // A fragment-read swizzled column offsets (elements); lds_byte = glob_byte ^ ((row&7)<<4)
  const int xorb    = (lrow & 7) << 4;
  const int col_el0 = ((lq * 16) ^ xorb) >> 1;   // kk=0
  const int col_el1 = col_el0 ^ 32;              // kk=1 (toggle byte bit 6)

  // A staging: srow = tid>>3 (0..63), pre-swizzled source column
  const int scol = ((tid & 7) ^ ((tid >> 3) & 7)) * 8;   // elements
  const int srow = tid >> 3;

  // B per-lane row base pointers (invariant): row = o0 + wn*64 + n*16 + lrow, k-sub = lq*8
  const uint16_t* bp[4];
#pragma unroll
  for (int n = 0; n < 4; ++n)
    bp[n] = Apk + (size_t)(o0 + wn * 64 + n * 16 + lrow) * KTOT + lq * 8;

  f32x4 acc[6][4] = {};
  bf16x8 bvA[8], bvB[8];   // [kk*4 + n]

#define STAGEA(u) do {                                                                \
    if ((u) < NTIL) {                                                                 \
      const int cb_  = (u) / 9;                                                       \
      const int tap_ = (u) - cb_ * 9;                                                 \
      const int off_ = (tap_ / 3) * QW + tap_ % 3;                                    \
      const int c0_  = cb_ << 6;                                                      \
      uint16_t* sl = lds + ((u) % 3) * ASLOT;                                         \
      _Pragma("unroll")                                                               \
      for (int j = 0; j < 3; ++j)                                                     \
        gll16(Xb + (size_t)(qb + off_ + j * 64 + srow) * CIN + c0_ + scol,            \
              sl + j * 4096 + wid * 512);                                             \
    }                                                                                 \
  } while (0)

#define LOADB(u, BVL) do {                                                            \
    const int cbn_  = (u) / 9;                                                        \
    const int tapn_ = (u) - cbn_ * 9;                                                 \
    const int eoff_ = (tapn_ << 10) + (cbn_ << 6);                                    \
    _Pragma("unroll")                                                                 \
    for (int n = 0; n < 4; ++n) {                                                     \
      asm volatile("global_load_dwordx4 %0, %1, off"                                  \
                   : "=v"(BVL[n]) : "v"(bp[n] + eoff_) : "memory");                   \
      asm volatile("global_load_dwordx4 %0, %1, off"                                  \
                   : "=v"(BVL[4 + n]) : "v"(bp[n] + eoff_ + 32) : "memory");          \
    }                                                                                 \
  } while (0)

#define TILE(t, BVU, BVL, LAST) do {                                                  \
    if (LAST) asm volatile("s_waitcnt vmcnt(0)" ::: "memory");                        \
    else      asm volatile("s_waitcnt vmcnt(3)" ::: "memory");                        \
    asm volatile("s_barrier" ::: "memory");                                           \
    __builtin_amdgcn_sched_barrier(0);                                                \
    if (!(LAST)) { LOADB((t) + 1, BVL); STAGEA((t) + 2); }                            \
    const uint16_t* As = lds + ((t) % 3) * ASLOT;                                     \
    bf16x8 av[6];                                                                     \
    _Pragma("unroll")                                                                 \
    for (int m = 0; m < 6; ++m)                                                       \
      av[m] = *(const bf16x8*)(As + (wm * 96 + m * 16 + lrow) * 64 + col_el0);        \
    __builtin_amdgcn_s_setprio(1);                                                    \
    _Pragma("unroll")                                                                 \
    for (int m = 0; m < 6; ++m)                                                       \
      _Pragma("unroll")                                                               \
      for (int n = 0; n < 4; ++n)                                                     \
        acc[m][n] = __builtin_amdgcn_mfma_f32_16x16x32_bf16(                          \
            av[m], BVU[n], acc[m][n], 0, 0, 0);                                       \
    __builtin_amdgcn_s_setprio(0);                                                    \
    _Pragma("unroll")                                                                 \
    for (int m = 0; m < 6; ++m)                                                       \
      av[m] = *(const bf16x8*)(As + (wm * 96 + m * 16 + lrow) * 64 + col_el1);        \
    __builtin_amdgcn_s_setprio(1);                                                    \
    _Pragma("unroll")                                                                 \
    for (int m = 0; m < 6; ++m)                                                       \
      _Pragma("unroll")                                                               \
      for (int n = 0; n < 4; ++n)                                                     \
        acc[m][n] = __builtin_amdgcn_mfma_f32_16x16x32_bf16(                          \
            av[m], BVU[4 + n], acc[m][n], 0, 0, 0);                                   \
    __builtin_amdgcn_s_setprio(0);                                                    \
  } while (0)

  // prologue: B(0) first (so vmcnt(3) at tile 0 drains it), then A(0), A(1)
  LOADB(0, bvA);
  STAGEA(0);
  STAGEA(1);

  for (int tp = 0; tp < NTIL - 2; tp += 2) {
    TILE(tp,     bvA, bvB, false);
    TILE(tp + 1, bvB, bvA, false);
  }
  TILE(NTIL - 2, bvA, bvB, false);   // loads B(143), STAGEA(144) self-skips
  TILE(NTIL - 1, bvB, bvA, true);    // vmcnt(0), no issues

  // epilogue: bias + ReLU6 -> x1 bf16
  const int qr = lq * 4;
#pragma unroll
  for (int n = 0; n < 4; ++n) {
    const int o = o0 + wn * 64 + n * 16 + lrow;
    const float bias = b1[o];
#pragma unroll
    for (int m = 0; m < 6; ++m) {
#pragma unroll
      for (int v = 0; v < 4; ++v) {
        const int q = qb + wm * 96 + m * 16 + qr + v;
        float x = acc[m][n][v] + bias;
        x = fminf(fmaxf(x, 0.f), 6.f);
        x1[((size_t)batch * QT + q) * CMID + o] = f2bf(x);
      }
    }
  }
#undef TILE
#undef LOADB
#undef STAGEA
}

// ---------- conv2: out[b][h][w][j] = sum_o x1[q][o] * W2[j][o] + b2[j] ----------
__global__ __launch_bounds__(256, 2) void k_conv2(
    const uint16_t* __restrict__ x1, const uint16_t* __restrict__ W2p,
    const float* __restrict__ b2, float* __restrict__ out) {
  __shared__ __align__(16) uint16_t lA[128 * 64];
  __shared__ __align__(16) uint16_t lB[128 * 64];
  const int tid = threadIdx.x;
  const int wid = tid >> 6, lane = tid & 63;
  const int b = blockIdx.z, q0 = blockIdx.x * 128;
  const uint16_t* Ab = x1 + (size_t)b * QT * CMID;
  const int wm = wid >> 1, wn = wid & 1;
  const int lrow = lane & 15, lk = (lane >> 4) * 8;
  f32x4 acc[4][4] = {};

  for (int kt = 0; kt < 8; ++kt) {
    const int c0 = kt << 6;
#pragma unroll
    for (int i = 0; i < 4; ++i) {
      int wb = i * 256 + wid * 64;
      int chunk = wb + lane;
      int row = chunk >> 3, ch = chunk & 7;
      gll16(Ab + (size_t)(q0 + row) * CMID + c0 + ch * 8, lA + wb * 8);
      gll16(W2p + (size_t)row * CMID + c0 + ch * 8, lB + wb * 8);
    }
    __syncthreads();
#pragma unroll
    for (int kk = 0; kk < 2; ++kk) {
      bf16x8 av[4], bv[4];
#pragma unroll
      for (int mi = 0; mi < 4; ++mi)
        av[mi] = *(const bf16x8*)(lA + (wm * 64 + mi * 16 + lrow) * 64 + kk * 32 + lk);
#pragma unroll
      for (int ni = 0; ni < 4; ++ni)
        bv[ni] = *(const bf16x8*)(lB + (wn * 64 + ni * 16 + lrow) * 64 + kk * 32 + lk);
#pragma unroll
      for (int mi = 0; mi < 4; ++mi)
#pragma unroll
        for (int ni = 0; ni < 4; ++ni)
          acc[mi][ni] = __builtin_amdgcn_mfma_f32_16x16x32_bf16(av[mi], bv[ni], acc[mi][ni], 0, 0, 0);
    }
    __syncthreads();
  }

  const int qr = (lane >> 4) * 4;
#pragma unroll
  for (int ni = 0; ni < 4; ++ni) {
    int j = wn * 64 + ni * 16 + lrow;
    if (j < 120) {
      float bias = b2[j];
#pragma unroll
      for (int mi = 0; mi < 4; ++mi) {
#pragma unroll
        for (int v = 0; v < 4; ++v) {
          int q = q0 + wm * 64 + mi * 16 + qr + v;
          int h = q / QW, w = q - h * QW;
          if (h < 37 && w < 37) {
            out[((size_t)b * HW + h * 37 + w) * 120 + j] = acc[mi][ni][v] + bias;
          }
        }
      }
    }
  }
}

extern "C" void kernel_launch(void* const* d_in, const int* in_sizes, int n_in,
                              void* d_out, int out_size, void* d_ws, size_t ws_size,
                              hipStream_t stream) {
  const float* fmap = (const float*)d_in[0];
  const float* W1   = (const float*)d_in[1];
  const float* b1   = (const float*)d_in[2];
  const float* W2   = (const float*)d_in[3];
  const float* b2   = (const float*)d_in[4];
  float* out = (float*)d_out;

  uint8_t* ws = (uint8_t*)d_ws;
  const size_t XP_BYTES  = (size_t)16 * QP * CIN * 2;   // 52,953,088
  const size_t W1P_BYTES = (size_t)512 * KTOT * 2;      //  9,437,184
  const size_t W2P_BYTES = (size_t)128 * 512 * 2;       //    131,072
  uint16_t* Xp  = (uint16_t*)ws;
  uint16_t* Apk = (uint16_t*)(ws + XP_BYTES);
  uint16_t* W2p = (uint16_t*)(ws + XP_BYTES + W1P_BYTES);
  uint16_t* x1  = (uint16_t*)(ws + XP_BYTES + W1P_BYTES + W2P_BYTES);

  hipMemsetAsync(Xp, 0, XP_BYTES, stream);
  k_pad_transpose<<<dim3(43, 32, 16), dim3(32, 8), 0, stream>>>(fmap, Xp);
  k_pack_w1<<<dim3((512 * KTOT + 255) / 256), dim3(256), 0, stream>>>(W1, Apk);
  k_pack_w2<<<dim3(256), dim3(256), 0, stream>>>(W2, W2p);
  k_conv1<<<dim3(256), dim3(512), 0, stream>>>(Xp, Apk, b1, x1);
  k_conv2<<<dim3(12, 1, 16), dim3(256), 0, stream>>>(x1, W2p, b2, out);
}

// Round 8
// 283.596 us; speedup vs baseline: 1.4257x; 1.4257x over previous
//
#include <hip/hip_runtime.h>
#include <stdint.h>

#define HW   1369      // 37*37 output pixels
#define QW   39        // padded row width
#define QP   1616      // padded plane rows per (b) in Xp
#define QT   1536      // q rows in x1 (per batch)
#define CIN  1024
#define CMID 512
#define KTOT 9216      // 9 * 1024
#define NTIL 144       // K-tiles: 16 cblocks(64) * 9 taps, cblock-major tap-inner
#define SLOT 28672     // LDS slot stride (elements): A 192x64 + B 256x64 = 56KB

typedef float  f32x4  __attribute__((ext_vector_type(4)));
typedef __bf16 bf16x8 __attribute__((ext_vector_type(8)));

__device__ __forceinline__ uint16_t f2bf(float f) {
  uint32_t u = __float_as_uint(f);
  u += 0x7fffu + ((u >> 16) & 1u);
  return (uint16_t)(u >> 16);
}

// global -> LDS direct copy, 16B per lane. LDS dest = wave-uniform base + lane*16.
__device__ __forceinline__ void gll16(const void* g, void* l) {
  const __attribute__((address_space(1))) uint32_t* ga =
      (const __attribute__((address_space(1))) uint32_t*)(uintptr_t)g;
  __attribute__((address_space(3))) uint32_t* la =
      (__attribute__((address_space(3))) uint32_t*)(uint32_t)(uintptr_t)l;
  __builtin_amdgcn_global_load_lds(ga, la, 16, 0, 0);
}

// ---------- prep: fmap [b][c][h][w] f32 -> Xp [b][q][c] bf16 (padded, zeroed border) ----------
__global__ void k_pad_transpose(const float* __restrict__ fmap, uint16_t* __restrict__ Xp) {
  __shared__ float t[32][33];
  const int b = blockIdx.z;
  const int c0 = blockIdx.y * 32;
  const int p0 = blockIdx.x * 32;
  const int tx = threadIdx.x, ty = threadIdx.y;
  const float* src = fmap + ((size_t)b * CIN + c0) * HW + p0;
#pragma unroll
  for (int i = 0; i < 4; ++i) {
    int cc = ty + i * 8;
    t[cc][tx] = (p0 + tx < HW) ? src[(size_t)cc * HW + tx] : 0.f;
  }
  __syncthreads();
#pragma unroll
  for (int i = 0; i < 4; ++i) {
    int pl = ty + i * 8;
    int p = p0 + pl;
    if (p < HW) {
      int h = p / 37, w = p - h * 37;
      int q = (h + 1) * QW + (w + 1);
      Xp[((size_t)b * QP + q) * CIN + c0 + tx] = f2bf(t[tx][pl]);
    }
  }
}

// ---------- prep: W1 [o][c][3][3] f32 -> Apk [o][r*1024+c] bf16 ----------
__global__ void k_pack_w1(const float* __restrict__ W1, uint16_t* __restrict__ Apk) {
  int idx = blockIdx.x * 256 + threadIdx.x;
  if (idx >= 512 * KTOT) return;
  int o = idx / KTOT, k = idx - o * KTOT;
  int r = k >> 10, c = k & 1023;
  Apk[idx] = f2bf(W1[((size_t)o * CIN + c) * 9 + r]);
}

// ---------- prep: W2 [120][512] f32 -> W2p [128][512] bf16 ----------
__global__ void k_pack_w2(const float* __restrict__ W2, uint16_t* __restrict__ W2p) {
  int idx = blockIdx.x * 256 + threadIdx.x;
  int j = idx >> 9, o = idx & 511;
  W2p[idx] = (j < 120) ? f2bf(W2[j * 512 + o]) : (uint16_t)0;
}

// ---------- conv1: implicit GEMM, 4-phase schedule (m201-style) ----------
// BM=192 x BN=256 x BK=64, 8 waves (2M x 4N, wave 96x64), 2 LDS slots, 256 blocks.
// Tile top: vmcnt(0) (drain stage(t), issued at top of t-1) + barrier, then issue
// ALL 7 stage loads of t+1 (full-tile latency cover).
// 4 phases: {ds_read frags ; barrier ; lgkmcnt(0)+sched_barrier ; setprio 12 MFMA ; barrier}.
// Per-phase lgkm waits cover only own reads -> waves de-phase, LDS reads overlap MFMA.
__global__ __launch_bounds__(512, 1) void k_conv1(
    const uint16_t* __restrict__ Xp, const uint16_t* __restrict__ Apk,
    const float* __restrict__ b1, uint16_t* __restrict__ x1) {
  __shared__ __align__(16) uint16_t lds[2 * SLOT];   // 114688 B

  const int tid  = threadIdx.x;
  const int wid  = tid >> 6, lane = tid & 63;
  const int lrow = lane & 15, lq = lane >> 4;
  const int wm   = wid >> 2,  wn = wid & 3;           // 2M x 4N

  // grid: 256 blocks = 8 XCDs x 32, mt-major within XCD
  const int bid = blockIdx.x;
  const int g   = (bid & 7) * 32 + (bid >> 3);
  const int mt  = g >> 1, nt = g & 1;
  const int batch = mt >> 3, qb = (mt & 7) * 192;
  const int o0 = nt * 256;
  const uint16_t* Xb = Xp + (size_t)batch * QP * CIN;

  // fragment-read swizzled column offsets (elements); lds_byte = glob_byte ^ ((row&7)<<4)
  const int xorb    = (lrow & 7) << 4;
  const int col_el0 = ((lq * 16) ^ xorb) >> 1;   // kk=0
  const int col_el1 = col_el0 ^ 32;              // kk=1 (toggle byte bit 6)

  // staging: srow = tid>>3 (0..63), pre-swizzled source column
  const int scol = ((tid & 7) ^ ((tid >> 3) & 7)) * 8;   // elements
  const int srow = tid >> 3;

  f32x4 acc[6][4] = {};

#define STAGE(u) do {                                                                 \
    if ((u) < NTIL) {                                                                 \
      const int cb_  = (u) / 9;                                                       \
      const int tap_ = (u) - cb_ * 9;                                                 \
      const int off_ = (tap_ / 3) * QW + tap_ % 3;                                    \
      const int c0_  = cb_ << 6;                                                      \
      uint16_t* sl = lds + ((u) & 1) * SLOT;                                          \
      _Pragma("unroll")                                                               \
      for (int j = 0; j < 3; ++j)                                                     \
        gll16(Xb + (size_t)(qb + off_ + j * 64 + srow) * CIN + c0_ + scol,            \
              sl + j * 4096 + wid * 512);                                             \
      _Pragma("unroll")                                                               \
      for (int j = 0; j < 4; ++j)                                                     \
        gll16(Apk + (size_t)(o0 + j * 64 + srow) * KTOT + (tap_ << 10) + c0_ + scol,  \
              sl + 12288 + j * 4096 + wid * 512);                                     \
    }                                                                                 \
  } while (0)

  // one phase: MH = m-half (0/1), KK = k-half (0/1); RDBV: load bv for this KK
#define PHASE(MH, KK, RDBV) do {                                                      \
    const int ce = (KK) ? col_el1 : col_el0;                                          \
    bf16x8 av[3];                                                                     \
    if (RDBV) {                                                                       \
      _Pragma("unroll")                                                               \
      for (int n = 0; n < 4; ++n)                                                     \
        bv[n] = *(const bf16x8*)(Bs + (wn * 64 + n * 16 + lrow) * 64 + ce);           \
    }                                                                                 \
    _Pragma("unroll")                                                                 \
    for (int m = 0; m < 3; ++m)                                                       \
      av[m] = *(const bf16x8*)(As + (wm * 96 + (MH) * 48 + m * 16 + lrow) * 64 + ce); \
    asm volatile("s_barrier" ::: "memory");                                           \
    asm volatile("s_waitcnt lgkmcnt(0)" ::: "memory");                                \
    __builtin_amdgcn_sched_barrier(0);                                                \
    __builtin_amdgcn_s_setprio(1);                                                    \
    _Pragma("unroll")                                                                 \
    for (int m = 0; m < 3; ++m)                                                       \
      _Pragma("unroll")                                                               \
      for (int n = 0; n < 4; ++n)                                                     \
        acc[(MH) * 3 + m][n] = __builtin_amdgcn_mfma_f32_16x16x32_bf16(               \
            av[m], bv[n], acc[(MH) * 3 + m][n], 0, 0, 0);                             \
    __builtin_amdgcn_s_setprio(0);                                                    \
    asm volatile("s_barrier" ::: "memory");                                           \
    __builtin_amdgcn_sched_barrier(0);                                                \
  } while (0)

  // prologue: stage tile 0
  STAGE(0);

  for (int t = 0; t < NTIL; ++t) {
    const uint16_t* As = lds + (t & 1) * SLOT;
    const uint16_t* Bs = As + 12288;
    asm volatile("s_waitcnt vmcnt(0)" ::: "memory");   // stage(t) landed (own loads)
    asm volatile("s_barrier" ::: "memory");            // everyone's stage(t) landed
    __builtin_amdgcn_sched_barrier(0);
    STAGE(t + 1);                                      // full-tile latency cover
    bf16x8 bv[4];
    PHASE(0, 0, 1);   // loads bv(kk0), MFMA m0-2
    PHASE(1, 0, 0);   // reuses bv(kk0), MFMA m3-5
    PHASE(0, 1, 1);   // loads bv(kk1), MFMA m0-2
    PHASE(1, 1, 0);   // reuses bv(kk1), MFMA m3-5
  }

  // epilogue: bias + ReLU6 -> x1 bf16
  const int qr = lq * 4;
#pragma unroll
  for (int n = 0; n < 4; ++n) {
    const int o = o0 + wn * 64 + n * 16 + lrow;
    const float bias = b1[o];
#pragma unroll
    for (int m = 0; m < 6; ++m) {
#pragma unroll
      for (int v = 0; v < 4; ++v) {
        const int q = qb + wm * 96 + m * 16 + qr + v;
        float x = acc[m][n][v] + bias;
        x = fminf(fmaxf(x, 0.f), 6.f);
        x1[((size_t)batch * QT + q) * CMID + o] = f2bf(x);
      }
    }
  }
#undef PHASE
#undef STAGE
}

// ---------- conv2: out[b][h][w][j] = sum_o x1[q][o] * W2[j][o] + b2[j] ----------
__global__ __launch_bounds__(256, 2) void k_conv2(
    const uint16_t* __restrict__ x1, const uint16_t* __restrict__ W2p,
    const float* __restrict__ b2, float* __restrict__ out) {
  __shared__ __align__(16) uint16_t lA[128 * 64];
  __shared__ __align__(16) uint16_t lB[128 * 64];
  const int tid = threadIdx.x;
  const int wid = tid >> 6, lane = tid & 63;
  const int b = blockIdx.z, q0 = blockIdx.x * 128;
  const uint16_t* Ab = x1 + (size_t)b * QT * CMID;
  const int wm = wid >> 1, wn = wid & 1;
  const int lrow = lane & 15, lk = (lane >> 4) * 8;
  f32x4 acc[4][4] = {};

  for (int kt = 0; kt < 8; ++kt) {
    const int c0 = kt << 6;
#pragma unroll
    for (int i = 0; i < 4; ++i) {
      int wb = i * 256 + wid * 64;
      int chunk = wb + lane;
      int row = chunk >> 3, ch = chunk & 7;
      gll16(Ab + (size_t)(q0 + row) * CMID + c0 + ch * 8, lA + wb * 8);
      gll16(W2p + (size_t)row * CMID + c0 + ch * 8, lB + wb * 8);
    }
    __syncthreads();
#pragma unroll
    for (int kk = 0; kk < 2; ++kk) {
      bf16x8 av[4], bv[4];
#pragma unroll
      for (int mi = 0; mi < 4; ++mi)
        av[mi] = *(const bf16x8*)(lA + (wm * 64 + mi * 16 + lrow) * 64 + kk * 32 + lk);
#pragma unroll
      for (int ni = 0; ni < 4; ++ni)
        bv[ni] = *(const bf16x8*)(lB + (wn * 64 + ni * 16 + lrow) * 64 + kk * 32 + lk);
#pragma unroll
      for (int mi = 0; mi < 4; ++mi)
#pragma unroll
        for (int ni = 0; ni < 4; ++ni)
          acc[mi][ni] = __builtin_amdgcn_mfma_f32_16x16x32_bf16(av[mi], bv[ni], acc[mi][ni], 0, 0, 0);
    }
    __syncthreads();
  }

  const int qr = (lane >> 4) * 4;
#pragma unroll
  for (int ni = 0; ni < 4; ++ni) {
    int j = wn * 64 + ni * 16 + lrow;
    if (j < 120) {
      float bias = b2[j];
#pragma unroll
      for (int mi = 0; mi < 4; ++mi) {
#pragma unroll
        for (int v = 0; v < 4; ++v) {
          int q = q0 + wm * 64 + mi * 16 + qr + v;
          int h = q / QW, w = q - h * QW;
          if (h < 37 && w < 37) {
            out[((size_t)b * HW + h * 37 + w) * 120 + j] = acc[mi][ni][v] + bias;
          }
        }
      }
    }
  }
}

extern "C" void kernel_launch(void* const* d_in, const int* in_sizes, int n_in,
                              void* d_out, int out_size, void* d_ws, size_t ws_size,
                              hipStream_t stream) {
  const float* fmap = (const float*)d_in[0];
  const float* W1   = (const float*)d_in[1];
  const float* b1   = (const float*)d_in[2];
  const float* W2   = (const float*)d_in[3];
  const float* b2   = (const float*)d_in[4];
  float* out = (float*)d_out;

  uint8_t* ws = (uint8_t*)d_ws;
  const size_t XP_BYTES  = (size_t)16 * QP * CIN * 2;   // 52,953,088
  const size_t W1P_BYTES = (size_t)512 * KTOT * 2;      //  9,437,184
  const size_t W2P_BYTES = (size_t)128 * 512 * 2;       //    131,072
  uint16_t* Xp  = (uint16_t*)ws;
  uint16_t* Apk = (uint16_t*)(ws + XP_BYTES);
  uint16_t* W2p = (uint16_t*)(ws + XP_BYTES + W1P_BYTES);
  uint16_t* x1  = (uint16_t*)(ws + XP_BYTES + W1P_BYTES + W2P_BYTES);

  hipMemsetAsync(Xp, 0, XP_BYTES, stream);
  k_pad_transpose<<<dim3(43, 32, 16), dim3(32, 8), 0, stream>>>(fmap, Xp);
  k_pack_w1<<<dim3((512 * KTOT + 255) / 256), dim3(256), 0, stream>>>(W1, Apk);
  k_pack_w2<<<dim3(256), dim3(256), 0, stream>>>(W2, W2p);
  k_conv1<<<dim3(256), dim3(512), 0, stream>>>(Xp, Apk, b1, x1);
  k_conv2<<<dim3(12, 1, 16), dim3(256), 0, stream>>>(x1, W2p, b2, out);
}

// Round 9
// 263.284 us; speedup vs baseline: 1.5356x; 1.0772x over previous
//
#include <hip/hip_runtime.h>
#include <stdint.h>

#define HW   1369      // 37*37 output pixels
#define QW   39        // padded row width
#define QP   1616      // padded plane rows per (b) in Xp
#define QT   1536      // q rows in x1 (per batch)
#define CIN  1024
#define CMID 512
#define KTOT 9216      // 9 * 1024
#define NTIL 144       // K-tiles: 16 cblocks(64) * 9 taps, cblock-major tap-inner
#define ASL  12288     // A slot stride (elements): 192 x 64 (24 KB)
#define BBASE 36864    // B region base (elements) = 3 * ASL
#define BSL  16384     // B slot stride (elements): 256 x 64 (32 KB)

typedef float  f32x4  __attribute__((ext_vector_type(4)));
typedef __bf16 bf16x8 __attribute__((ext_vector_type(8)));

__device__ __forceinline__ uint16_t f2bf(float f) {
  uint32_t u = __float_as_uint(f);
  u += 0x7fffu + ((u >> 16) & 1u);
  return (uint16_t)(u >> 16);
}

// global -> LDS direct copy, 16B per lane. LDS dest = wave-uniform base + lane*16.
__device__ __forceinline__ void gll16(const void* g, void* l) {
  const __attribute__((address_space(1))) uint32_t* ga =
      (const __attribute__((address_space(1))) uint32_t*)(uintptr_t)g;
  __attribute__((address_space(3))) uint32_t* la =
      (__attribute__((address_space(3))) uint32_t*)(uint32_t)(uintptr_t)l;
  __builtin_amdgcn_global_load_lds(ga, la, 16, 0, 0);
}

// ---------- prep: fmap [b][c][h][w] f32 -> Xp [b][q][c] bf16 (padded, zeroed border) ----------
__global__ void k_pad_transpose(const float* __restrict__ fmap, uint16_t* __restrict__ Xp) {
  __shared__ float t[32][33];
  const int b = blockIdx.z;
  const int c0 = blockIdx.y * 32;
  const int p0 = blockIdx.x * 32;
  const int tx = threadIdx.x, ty = threadIdx.y;
  const float* src = fmap + ((size_t)b * CIN + c0) * HW + p0;
#pragma unroll
  for (int i = 0; i < 4; ++i) {
    int cc = ty + i * 8;
    t[cc][tx] = (p0 + tx < HW) ? src[(size_t)cc * HW + tx] : 0.f;
  }
  __syncthreads();
#pragma unroll
  for (int i = 0; i < 4; ++i) {
    int pl = ty + i * 8;
    int p = p0 + pl;
    if (p < HW) {
      int h = p / 37, w = p - h * 37;
      int q = (h + 1) * QW + (w + 1);
      Xp[((size_t)b * QP + q) * CIN + c0 + tx] = f2bf(t[tx][pl]);
    }
  }
}

// ---------- prep: W1 [o][c][3][3] f32 -> Apk [o][r*1024+c] bf16 ----------
__global__ void k_pack_w1(const float* __restrict__ W1, uint16_t* __restrict__ Apk) {
  int idx = blockIdx.x * 256 + threadIdx.x;
  if (idx >= 512 * KTOT) return;
  int o = idx / KTOT, k = idx - o * KTOT;
  int r = k >> 10, c = k & 1023;
  Apk[idx] = f2bf(W1[((size_t)o * CIN + c) * 9 + r]);
}

// ---------- prep: W2 [120][512] f32 -> W2p [128][512] bf16 ----------
__global__ void k_pack_w2(const float* __restrict__ W2, uint16_t* __restrict__ W2p) {
  int idx = blockIdx.x * 256 + threadIdx.x;
  int j = idx >> 9, o = idx & 511;
  W2p[idx] = (j < 120) ? f2bf(W2[j * 512 + o]) : (uint16_t)0;
}

// ---------- conv1: implicit GEMM, minimum-sync tile ----------
// BM=192 x BN=256 x BK=64, 8 waves (2M x 4N, wave 96x64), 256 blocks.
// LDS: A = 3 slots x 24KB (staged t+2), B = 2 slots x 32KB (staged t+1) = 136KB.
// Slot being written is NEVER the slot being read -> NO mid-tile drain.
// Per tile: ONE counted vmcnt(3) + ONE barrier; body is plain C++ ds_reads +
// MFMAs, compiler-scheduled (fine-grained lgkm waits), so the 2 waves/SIMD
// slip and overlap LDS reads with MFMA.
// Per-wave VMEM FIFO: [.., A(t):3, B(t):4, A(t+1):3] at tile top -> vmcnt(3)
// drains A(t)+B(t), leaves A(t+1). Last tile: vmcnt(0).
__global__ __launch_bounds__(512, 1) void k_conv1(
    const uint16_t* __restrict__ Xp, const uint16_t* __restrict__ Apk,
    const float* __restrict__ b1, uint16_t* __restrict__ x1) {
  __shared__ __align__(16) uint16_t lds[BBASE + 2 * BSL];   // 139264 B

  const int tid  = threadIdx.x;
  const int wid  = tid >> 6, lane = tid & 63;
  const int lrow = lane & 15, lq = lane >> 4;
  const int wm   = wid >> 2,  wn = wid & 3;           // 2M x 4N

  // grid: 256 blocks = 8 XCDs x 32, mt-major within XCD
  const int bid = blockIdx.x;
  const int g   = (bid & 7) * 32 + (bid >> 3);
  const int mt  = g >> 1, nt = g & 1;
  const int batch = mt >> 3, qb = (mt & 7) * 192;
  const int o0 = nt * 256;
  const uint16_t* Xb = Xp + (size_t)batch * QP * CIN;

  // fragment-read swizzled column offsets (elements); lds_byte = glob_byte ^ ((row&7)<<4)
  const int xorb    = (lrow & 7) << 4;
  const int col_el0 = ((lq * 16) ^ xorb) >> 1;   // kk=0
  const int col_el1 = col_el0 ^ 32;              // kk=1 (toggle byte bit 6)

  // staging: srow = tid>>3 (0..63), pre-swizzled source column
  const int scol = ((tid & 7) ^ ((tid >> 3) & 7)) * 8;   // elements
  const int srow = tid >> 3;

  f32x4 acc[6][4] = {};

#define STAGEA(u) do {                                                                \
    if ((u) < NTIL) {                                                                 \
      const int cb_  = (u) / 9;                                                       \
      const int tap_ = (u) - cb_ * 9;                                                 \
      const int off_ = (tap_ / 3) * QW + tap_ % 3;                                    \
      const int c0_  = cb_ << 6;                                                      \
      uint16_t* sl = lds + ((u) % 3) * ASL;                                           \
      _Pragma("unroll")                                                               \
      for (int j = 0; j < 3; ++j)                                                     \
        gll16(Xb + (size_t)(qb + off_ + j * 64 + srow) * CIN + c0_ + scol,            \
              sl + j * 4096 + wid * 512);                                             \
    }                                                                                 \
  } while (0)

#define STAGEB(u) do {                                                                \
    if ((u) < NTIL) {                                                                 \
      const int cb_  = (u) / 9;                                                       \
      const int tap_ = (u) - cb_ * 9;                                                 \
      const int c0_  = cb_ << 6;                                                      \
      uint16_t* sl = lds + BBASE + ((u) & 1) * BSL;                                   \
      _Pragma("unroll")                                                               \
      for (int j = 0; j < 4; ++j)                                                     \
        gll16(Apk + (size_t)(o0 + j * 64 + srow) * KTOT + (tap_ << 10) + c0_ + scol,  \
              sl + j * 4096 + wid * 512);                                             \
    }                                                                                 \
  } while (0)

  // prologue: FIFO order must be B(0), A(0), A(1) so vmcnt(3) at tile 0 is correct
  STAGEB(0);
  STAGEA(0);
  STAGEA(1);

  for (int t = 0; t < NTIL; ++t) {
    const uint16_t* As = lds + (t % 3) * ASL;
    const uint16_t* Bs = lds + BBASE + (t & 1) * BSL;
    if (t == NTIL - 1) asm volatile("s_waitcnt vmcnt(0)" ::: "memory");
    else               asm volatile("s_waitcnt vmcnt(3)" ::: "memory");
    asm volatile("s_barrier" ::: "memory");   // publish stage(t); read-done for t-1
    __builtin_amdgcn_sched_barrier(0);
    STAGEB(t + 1);                            // writes B slot (t+1)&1 != read slot t&1
    STAGEA(t + 2);                            // writes A slot (t+2)%3 != t%3,(t+1)%3

    bf16x8 av0[6], av1[6], bv0[4], bv1[4];
#pragma unroll
    for (int n = 0; n < 4; ++n) {
      const uint16_t* br = Bs + (wn * 64 + n * 16 + lrow) * 64;
      bv0[n] = *(const bf16x8*)(br + col_el0);
      bv1[n] = *(const bf16x8*)(br + col_el1);
    }
#pragma unroll
    for (int m = 0; m < 6; ++m) {
      const uint16_t* ar = As + (wm * 96 + m * 16 + lrow) * 64;
      av0[m] = *(const bf16x8*)(ar + col_el0);
      av1[m] = *(const bf16x8*)(ar + col_el1);
    }
    __builtin_amdgcn_s_setprio(1);
#pragma unroll
    for (int m = 0; m < 6; ++m)
#pragma unroll
      for (int n = 0; n < 4; ++n)
        acc[m][n] = __builtin_amdgcn_mfma_f32_16x16x32_bf16(av0[m], bv0[n], acc[m][n], 0, 0, 0);
#pragma unroll
    for (int m = 0; m < 6; ++m)
#pragma unroll
      for (int n = 0; n < 4; ++n)
        acc[m][n] = __builtin_amdgcn_mfma_f32_16x16x32_bf16(av1[m], bv1[n], acc[m][n], 0, 0, 0);
    __builtin_amdgcn_s_setprio(0);
  }

  // epilogue: bias + ReLU6 -> x1 bf16
  const int qr = lq * 4;
#pragma unroll
  for (int n = 0; n < 4; ++n) {
    const int o = o0 + wn * 64 + n * 16 + lrow;
    const float bias = b1[o];
#pragma unroll
    for (int m = 0; m < 6; ++m) {
#pragma unroll
      for (int v = 0; v < 4; ++v) {
        const int q = qb + wm * 96 + m * 16 + qr + v;
        float x = acc[m][n][v] + bias;
        x = fminf(fmaxf(x, 0.f), 6.f);
        x1[((size_t)batch * QT + q) * CMID + o] = f2bf(x);
      }
    }
  }
#undef STAGEB
#undef STAGEA
}

// ---------- conv2: out[b][h][w][j] = sum_o x1[q][o] * W2[j][o] + b2[j] ----------
__global__ __launch_bounds__(256, 2) void k_conv2(
    const uint16_t* __restrict__ x1, const uint16_t* __restrict__ W2p,
    const float* __restrict__ b2, float* __restrict__ out) {
  __shared__ __align__(16) uint16_t lA[128 * 64];
  __shared__ __align__(16) uint16_t lB[128 * 64];
  const int tid = threadIdx.x;
  const int wid = tid >> 6, lane = tid & 63;
  const int b = blockIdx.z, q0 = blockIdx.x * 128;
  const uint16_t* Ab = x1 + (size_t)b * QT * CMID;
  const int wm = wid >> 1, wn = wid & 1;
  const int lrow = lane & 15, lk = (lane >> 4) * 8;
  f32x4 acc[4][4] = {};

  for (int kt = 0; kt < 8; ++kt) {
    const int c0 = kt << 6;
#pragma unroll
    for (int i = 0; i < 4; ++i) {
      int wb = i * 256 + wid * 64;
      int chunk = wb + lane;
      int row = chunk >> 3, ch = chunk & 7;
      gll16(Ab + (size_t)(q0 + row) * CMID + c0 + ch * 8, lA + wb * 8);
      gll16(W2p + (size_t)row * CMID + c0 + ch * 8, lB + wb * 8);
    }
    __syncthreads();
#pragma unroll
    for (int kk = 0; kk < 2; ++kk) {
      bf16x8 av[4], bv[4];
#pragma unroll
      for (int mi = 0; mi < 4; ++mi)
        av[mi] = *(const bf16x8*)(lA + (wm * 64 + mi * 16 + lrow) * 64 + kk * 32 + lk);
#pragma unroll
      for (int ni = 0; ni < 4; ++ni)
        bv[ni] = *(const bf16x8*)(lB + (wn * 64 + ni * 16 + lrow) * 64 + kk * 32 + lk);
#pragma unroll
      for (int mi = 0; mi < 4; ++mi)
#pragma unroll
        for (int ni = 0; ni < 4; ++ni)
          acc[mi][ni] = __builtin_amdgcn_mfma_f32_16x16x32_bf16(av[mi], bv[ni], acc[mi][ni], 0, 0, 0);
    }
    __syncthreads();
  }

  const int qr = (lane >> 4) * 4;
#pragma unroll
  for (int ni = 0; ni < 4; ++ni) {
    int j = wn * 64 + ni * 16 + lrow;
    if (j < 120) {
      float bias = b2[j];
#pragma unroll
      for (int mi = 0; mi < 4; ++mi) {
#pragma unroll
        for (int v = 0; v < 4; ++v) {
          int q = q0 + wm * 64 + mi * 16 + qr + v;
          int h = q / QW, w = q - h * QW;
          if (h < 37 && w < 37) {
            out[((size_t)b * HW + h * 37 + w) * 120 + j] = acc[mi][ni][v] + bias;
          }
        }
      }
    }
  }
}

extern "C" void kernel_launch(void* const* d_in, const int* in_sizes, int n_in,
                              void* d_out, int out_size, void* d_ws, size_t ws_size,
                              hipStream_t stream) {
  const float* fmap = (const float*)d_in[0];
  const float* W1   = (const float*)d_in[1];
  const float* b1   = (const float*)d_in[2];
  const float* W2   = (const float*)d_in[3];
  const float* b2   = (const float*)d_in[4];
  float* out = (float*)d_out;

  uint8_t* ws = (uint8_t*)d_ws;
  const size_t XP_BYTES  = (size_t)16 * QP * CIN * 2;   // 52,953,088
  const size_t W1P_BYTES = (size_t)512 * KTOT * 2;      //  9,437,184
  const size_t W2P_BYTES = (size_t)128 * 512 * 2;       //    131,072
  uint16_t* Xp  = (uint16_t*)ws;
  uint16_t* Apk = (uint16_t*)(ws + XP_BYTES);
  uint16_t* W2p = (uint16_t*)(ws + XP_BYTES + W1P_BYTES);
  uint16_t* x1  = (uint16_t*)(ws + XP_BYTES + W1P_BYTES + W2P_BYTES);

  hipMemsetAsync(Xp, 0, XP_BYTES, stream);
  k_pad_transpose<<<dim3(43, 32, 16), dim3(32, 8), 0, stream>>>(fmap, Xp);
  k_pack_w1<<<dim3((512 * KTOT + 255) / 256), dim3(256), 0, stream>>>(W1, Apk);
  k_pack_w2<<<dim3(256), dim3(256), 0, stream>>>(W2, W2p);
  k_conv1<<<dim3(256), dim3(512), 0, stream>>>(Xp, Apk, b1, x1);
  k_conv2<<<dim3(12, 1, 16), dim3(256), 0, stream>>>(x1, W2p, b2, out);
}